// Round 10
// baseline (122.024 us; speedup 1.0000x reference)
//
#include <hip/hip_runtime.h>
#include <hip/hip_bf16.h>
#include <math.h>

typedef __bf16 bf16_t;
typedef __bf16 bf16x4 __attribute__((ext_vector_type(4)));
typedef __bf16 bf16x8 __attribute__((ext_vector_type(8)));
typedef float f32x4 __attribute__((ext_vector_type(4)));

#define MFMA16(a, b, c) __builtin_amdgcn_mfma_f32_16x16x32_bf16((a), (b), (c), 0, 0, 0)
#define EXP2F(x) __builtin_amdgcn_exp2f(x)

__device__ __forceinline__ void gll16(const void* g, void* lds) {
    __builtin_amdgcn_global_load_lds((const __attribute__((address_space(1))) void*)g,
                                     (__attribute__((address_space(3))) void*)lds, 16, 0, 0);
}

// ---------------------------------------------------------------------------
// Prep kernel: blocks [0,4608): f32->bf16 convert of Q,K,V (1536 blocks each);
// blocks [4608,8640): transpose+convert 7 weights (576 blocks each);
// blocks 8640/8641: extract diag(W_pos)*SC / -diag(W_neg)*SC as f32 arrays.
// ---------------------------------------------------------------------------
struct PrepPtrs {
    const float* csrc[3];
    bf16_t* cdst[3];
    const float* wsrc[7];
    bf16_t* wdst[7];
    const float* dsrc[2];
    float* ddst[2];
};

__global__ __launch_bounds__(256) void prep_kernel(PrepPtrs p) {
    const int bx = blockIdx.x, tid = threadIdx.x;
    if (bx < 4608) {
        const int t = bx / 1536, i = (bx - t * 1536) * 256 + tid;
        const float4 u = ((const float4*)p.csrc[t])[i * 2];
        const float4 v = ((const float4*)p.csrc[t])[i * 2 + 1];
        bf16x8 o;
        o[0] = (bf16_t)u.x; o[1] = (bf16_t)u.y; o[2] = (bf16_t)u.z; o[3] = (bf16_t)u.w;
        o[4] = (bf16_t)v.x; o[5] = (bf16_t)v.y; o[6] = (bf16_t)v.z; o[7] = (bf16_t)v.w;
        ((bf16x8*)p.cdst[t])[i] = o;
    } else if (bx < 8640) {
        __shared__ float t[32][33];
        const int q = bx - 4608, wz = q / 576, rem = q - wz * 576;
        const int bxx = rem % 24, byy = rem / 24;
        const float* src = p.wsrc[wz];
        bf16_t* dst = p.wdst[wz];
        const int tx = tid & 31, ty = tid >> 5;
        const int x = bxx * 32 + tx;
        const int y0 = byy * 32;
#pragma unroll
        for (int j = 0; j < 4; ++j)
            t[ty + j * 8][tx] = src[(size_t)(y0 + ty + j * 8) * 768 + x];
        __syncthreads();
        const int ox = byy * 32 + tx;
        const int oy0 = bxx * 32;
#pragma unroll
        for (int j = 0; j < 4; ++j)
            dst[(size_t)(oy0 + ty + j * 8) * 768 + ox] = (bf16_t)t[tx][ty + j * 8];
    } else {
        const int s = bx - 8640;
        const float SC = 1.4426950408889634f / (8.0f + 1e-6f);
        const float sc = s ? -SC : SC;
        const float* src = p.dsrc[s];
        float* dst = p.ddst[s];
        for (int i = tid; i < 512; i += 256) dst[i] = src[(size_t)i * 513] * sc;
    }
}

// ---------------------------------------------------------------------------
// v [4096,768] bf16 (head-major cols) -> Vt [96][64][512] bf16 (d-major)
// Coalesced via LDS bounce (r5-proven, ~4 us).
// ---------------------------------------------------------------------------
__global__ __launch_bounds__(256) void transpose_v_kernel(const bf16_t* __restrict__ vb,
                                                          bf16_t* __restrict__ Vt) {
    __shared__ bf16_t t[32][34];
    const int bh = blockIdx.z, b = bh / 12, h = bh % 12;
    const int l0 = blockIdx.x * 32, d0 = blockIdx.y * 32;
    const int tx = threadIdx.x, ty = threadIdx.y;
#pragma unroll
    for (int j = 0; j < 4; ++j)
        t[ty + j * 8][tx] = vb[(size_t)(b * 512 + l0 + ty + j * 8) * 768 + h * 64 + d0 + tx];
    __syncthreads();
#pragma unroll
    for (int j = 0; j < 4; ++j)
        Vt[((size_t)bh * 64 + d0 + ty + j * 8) * 512 + l0 + tx] = t[tx][ty + j * 8];
}

// ---------------------------------------------------------------------------
// GEMM: C[M,N] = A[M,K] @ Bt[N,K]^T, bf16, BM=128 x BN=96 x BK=64, 4 waves
// (2x2, wave sub-tile 64x48, acc[4][3]). N=768 = 8 col-tiles -> grids are
// exact multiples of 256 blocks = zero tail at 2-3 blocks/CU.
// Staging via global_load_lds (16B) with XOR-involution; XCD-bijective
// block swizzle keeps A-row-panels + weight in one XCD's L2.
// RESMODE: 0 none, 1 f32 residual, 2 bf16 residual. OUTMODE: 0 f32, 1 bf16.
// All epilogue stores coalesced (row-major C only — no scattered layouts;
// VTZ experiment r6-r9 cost ~25 us in TA segment serialization).
// ---------------------------------------------------------------------------
struct GemmB {
    const bf16_t* A[3];
    const bf16_t* Bt[3];
    const float* bias;
    const float* Res[3];
    const bf16_t* ResB[3];
    float* Cf[3];
    bf16_t* Cb[3];
};

template <bool HAS_BIAS, bool RELU, int RESMODE, int OUTMODE>
__global__ __launch_bounds__(256, 3) void gemm2(GemmB p, int M, int K, int N) {
    __shared__ __align__(16) bf16_t As[128 * 64];  // 16 KB, rows of 128 B
    __shared__ __align__(16) bf16_t Bs[96 * 64];   // 12 KB, rows of 128 B
    const int z = blockIdx.z;
    const bf16_t* __restrict__ A = p.A[z];
    const bf16_t* __restrict__ Bt = p.Bt[z];
    const int tid = threadIdx.x, w = tid >> 6, l = tid & 63, l16 = l & 15, lk = l >> 4;
    const int wr = w >> 1, wc = w & 1;

    // XCD-bijective swizzle (nwg % 8 == 0 in all launches here)
    const int gx = gridDim.x, nwg = gx * gridDim.y;
    int flat = blockIdx.x + gx * blockIdx.y;
    flat = (flat & 7) * (nwg >> 3) + (flat >> 3);
    const int row0 = (flat / gx) * 128, col0 = (flat % gx) * 96;
    f32x4 acc[4][3] = {};

    const int lofs = l * 16;  // byte offset within a 1KB segment
    size_t aEl[4], bEl[3];
#pragma unroll
    for (int i = 0; i < 4; ++i) {
        const int off = (w * 4 + i) * 1024 + lofs;
        const int row = off >> 7;
        const int ch = ((off >> 4) & 7) ^ (row & 7);
        aEl[i] = (size_t)(row0 + row) * K + ch * 8;
    }
#pragma unroll
    for (int i = 0; i < 3; ++i) {
        const int off = (w * 3 + i) * 1024 + lofs;
        const int row = off >> 7;
        const int ch = ((off >> 4) & 7) ^ (row & 7);
        bEl[i] = (size_t)(col0 + row) * K + ch * 8;
    }

    for (int k0 = 0; k0 < K; k0 += 64) {
        __syncthreads();
#pragma unroll
        for (int i = 0; i < 4; ++i)
            gll16(A + aEl[i] + k0, (char*)As + (w * 4 + i) * 1024);
#pragma unroll
        for (int i = 0; i < 3; ++i)
            gll16(Bt + bEl[i] + k0, (char*)Bs + (w * 3 + i) * 1024);
        __syncthreads();

#pragma unroll
        for (int kk = 0; kk < 2; ++kk) {
            bf16x8 af[4], bfr[3];
#pragma unroll
            for (int mt = 0; mt < 4; ++mt) {
                const int ar = wr * 64 + mt * 16 + l16;
                af[mt] = *(const bf16x8*)((const char*)As + ar * 128 +
                                          (((kk * 4 + lk) ^ (ar & 7)) << 4));
            }
#pragma unroll
            for (int nt = 0; nt < 3; ++nt) {
                const int br = wc * 48 + nt * 16 + l16;
                bfr[nt] = *(const bf16x8*)((const char*)Bs + br * 128 +
                                           (((kk * 4 + lk) ^ (br & 7)) << 4));
            }
#pragma unroll
            for (int mt = 0; mt < 4; ++mt)
#pragma unroll
                for (int nt = 0; nt < 3; ++nt)
                    acc[mt][nt] = MFMA16(af[mt], bfr[nt], acc[mt][nt]);
        }
    }

#pragma unroll
    for (int mt = 0; mt < 4; ++mt)
#pragma unroll
        for (int nt = 0; nt < 3; ++nt)
#pragma unroll
            for (int i = 0; i < 4; ++i) {
                const int row = row0 + wr * 64 + mt * 16 + lk * 4 + i;
                const int col = col0 + wc * 48 + nt * 16 + l16;
                float val = acc[mt][nt][i];
                if constexpr (HAS_BIAS) val += p.bias[col];
                if constexpr (RELU) val = fmaxf(val, 0.0f);
                const size_t o = (size_t)row * N + col;
                if constexpr (RESMODE == 1) val += p.Res[z][o];
                if constexpr (RESMODE == 2) val += (float)p.ResB[z][o];
                if constexpr (OUTMODE == 0) p.Cf[z][o] = val;
                else p.Cb[z][o] = (bf16_t)val;
            }
}

// ---------------------------------------------------------------------------
// Fused dual-softmax attention v6. Block = (bh, 64 q-rows), 4 waves:
// wave = (row-half, sign); each wave owns 32 q-rows x all keys x one sign.
// 8 chunks of 64 keys; K/Vt double-buffered in LDS (gll16 + XOR involution);
// stage(c+1) issued before compute(c). 32 MFMA per barrier; K/V ds_reads
// shared across the wave's two 16-row groups. Grid (96,8) = 768 blocks =
// exactly 3/CU, single pass. diag scales pre-packed as f32 (coalesced).
// No max pass (logits bounded, validated r2-r9).
// ---------------------------------------------------------------------------
__global__ __launch_bounds__(256, 3) void attn_kernel(const bf16_t* __restrict__ qb,
                                                      const bf16_t* __restrict__ kb,
                                                      const bf16_t* __restrict__ Vt,
                                                      const float* __restrict__ dPos,
                                                      const float* __restrict__ dNeg,
                                                      bf16_t* __restrict__ Vpb,
                                                      bf16_t* __restrict__ Vnb) {
    __shared__ __align__(16) bf16_t Ks[2][64 * 64];  // 2 x 8 KB (64 key-rows x 128 B)
    __shared__ __align__(16) bf16_t Vs[2][64 * 64];  // 2 x 8 KB (64 d-rows x 128 B)
    __shared__ __align__(16) bf16_t Ps[4][32][72];   // 18 KB wave-private P
    const int tid = threadIdx.x, w = tid >> 6, l = tid & 63, l16 = l & 15, lk = l >> 4;
    const int rh = w >> 1, sgn = w & 1;
    const int bh = blockIdx.x, qt = blockIdx.y, b = bh / 12, h = bh % 12;
    const int q0 = qt * 64 + rh * 32;
    const float* __restrict__ Wd = sgn ? dNeg : dPos;

    // Q fragments for this wave's 32 rows (2 row-groups), loaded once
    const size_t qbase = ((size_t)(b * 512 + q0)) * 768 + h * 64;
    bf16x8 qf[2][2];
#pragma unroll
    for (int rt = 0; rt < 2; ++rt)
#pragma unroll
        for (int ks = 0; ks < 2; ++ks)
            qf[rt][ks] =
                *(const bf16x8*)(qb + qbase + (size_t)(rt * 16 + l16) * 768 + ks * 32 + lk * 8);

    // staging source offsets (pre-swizzled); wave stages segs {2w, 2w+1}
    const size_t kbase0 = ((size_t)b * 512) * 768 + h * 64;
    const size_t vtb = (size_t)bh * 64 * 512;
    size_t kEl[2], vEl[2];
    int seg[2];
#pragma unroll
    for (int i = 0; i < 2; ++i) {
        seg[i] = w * 2 + i;
        const int off = seg[i] * 1024 + l * 16;
        const int row = off >> 7, slot = (off >> 4) & 7;
        kEl[i] = (size_t)row * 768 + (size_t)((slot ^ (row & 7)) * 8);
        vEl[i] = (size_t)row * 512 + (size_t)((slot ^ (row & 7)) * 8);
    }

    auto stage = [&](int c, int buf) {
#pragma unroll
        for (int i = 0; i < 2; ++i) {
            gll16(kb + kbase0 + (size_t)c * 64 * 768 + kEl[i], (char*)&Ks[buf][0] + seg[i] * 1024);
            gll16(Vt + vtb + (size_t)c * 64 + vEl[i], (char*)&Vs[buf][0] + seg[i] * 1024);
        }
    };

    f32x4 pacc[2][4] = {};
    float sm[2][4] = {};

    stage(0, 0);
    __syncthreads();

    for (int c = 0; c < 8; ++c) {
        const int buf = c & 1;
        if (c < 7) stage(c + 1, buf ^ 1);

        float dv[4];
#pragma unroll
        for (int nt = 0; nt < 4; ++nt) dv[nt] = Wd[c * 64 + nt * 16 + l16];

        // --- QK^T on staged K: 8 ds_reads feed 16 MFMA (shared across rt) ---
        f32x4 sacc[2][4] = {};
        __builtin_amdgcn_s_setprio(1);
#pragma unroll
        for (int nt = 0; nt < 4; ++nt) {
            const int kr = nt * 16 + l16;
            const bf16x8 kv0 =
                *(const bf16x8*)((const char*)&Ks[buf][0] + kr * 128 + ((lk ^ (kr & 7)) << 4));
            const bf16x8 kv1 =
                *(const bf16x8*)((const char*)&Ks[buf][0] + kr * 128 + (((4 + lk) ^ (kr & 7)) << 4));
            sacc[0][nt] = MFMA16(qf[0][0], kv0, sacc[0][nt]);
            sacc[0][nt] = MFMA16(qf[0][1], kv1, sacc[0][nt]);
            sacc[1][nt] = MFMA16(qf[1][0], kv0, sacc[1][nt]);
            sacc[1][nt] = MFMA16(qf[1][1], kv1, sacc[1][nt]);
        }
        __builtin_amdgcn_s_setprio(0);

        // --- exp2 (no max; logits bounded), store P, accumulate sums ---
#pragma unroll
        for (int rt = 0; rt < 2; ++rt)
#pragma unroll
            for (int nt = 0; nt < 4; ++nt)
#pragma unroll
                for (int i = 0; i < 4; ++i) {
                    const float e = EXP2F(sacc[rt][nt][i] * dv[nt]);
                    Ps[w][rt * 16 + lk * 4 + i][nt * 16 + l16] = (bf16_t)e;
                    sm[rt][i] += e;
                }

        // --- PV on staged V: 8 V ds_reads feed 16 MFMA (shared across rt) ---
        __builtin_amdgcn_s_setprio(1);
#pragma unroll
        for (int kt = 0; kt < 2; ++kt) {
            const bf16x8 pa0 = *(const bf16x8*)&Ps[w][l16][kt * 32 + lk * 8];
            const bf16x8 pa1 = *(const bf16x8*)&Ps[w][16 + l16][kt * 32 + lk * 8];
#pragma unroll
            for (int nd = 0; nd < 4; ++nd) {
                const int dr = nd * 16 + l16;
                const bf16x8 vv = *(const bf16x8*)((const char*)&Vs[buf][0] + dr * 128 +
                                                   (((kt * 4 + lk) ^ (dr & 7)) << 4));
                pacc[0][nd] = MFMA16(pa0, vv, pacc[0][nd]);
                pacc[1][nd] = MFMA16(pa1, vv, pacc[1][nd]);
            }
        }
        __builtin_amdgcn_s_setprio(0);

        if (c < 7) __syncthreads();  // drains vmcnt (stage c+1) + guards buf reuse
    }

    // --- finish row sums (keys spread across l16 lanes only) ---
#pragma unroll
    for (int off = 1; off < 16; off <<= 1)
#pragma unroll
        for (int rt = 0; rt < 2; ++rt)
#pragma unroll
            for (int i = 0; i < 4; ++i) sm[rt][i] += __shfl_xor(sm[rt][i], off, 64);

    // --- normalize + store this wave's complete 32x64 output ---
    bf16_t* __restrict__ Out = sgn ? Vnb : Vpb;
#pragma unroll
    for (int rt = 0; rt < 2; ++rt)
#pragma unroll
        for (int i = 0; i < 4; ++i) {
            const float r = (sgn ? -1.0f : 1.0f) / sm[rt][i];
            const size_t o = ((size_t)(b * 512 + q0 + rt * 16 + lk * 4 + i)) * 768 + h * 64;
#pragma unroll
            for (int nd = 0; nd < 4; ++nd) Out[o + nd * 16 + l16] = (bf16_t)(pacc[rt][nd][i] * r);
        }
}

// ---------------------------------------------------------------------------
extern "C" void kernel_launch(void* const* d_in, const int* in_sizes, int n_in,
                              void* d_out, int out_size, void* d_ws, size_t ws_size,
                              hipStream_t stream) {
    const float* Q = (const float*)d_in[0];
    const float* K = (const float*)d_in[1];
    const float* V = (const float*)d_in[2];
    const float* W_q = (const float*)d_in[3];
    const float* W_k = (const float*)d_in[4];
    const float* W_v = (const float*)d_in[5];
    const float* Wpos = (const float*)d_in[6];
    const float* Wneg = (const float*)d_in[7];
    const float* W_o = (const float*)d_in[8];
    const float* W_o2 = (const float*)d_in[9];
    const float* w1 = (const float*)d_in[10];
    const float* b1 = (const float*)d_in[11];
    const float* w2 = (const float*)d_in[12];
    const float* b2 = (const float*)d_in[13];
    float* out = (float*)d_out;

    char* ws = (char*)d_ws;
    const size_t act_b = (size_t)4096 * 768 * 2;  // 6.29 MB
    const size_t wt_b = (size_t)768 * 768 * 2;
    bf16_t* Qb = (bf16_t*)(ws + 0 * act_b);       // later: Vpb
    bf16_t* Kb = (bf16_t*)(ws + 1 * act_b);       // later: Vnb
    bf16_t* Vb = (bf16_t*)(ws + 2 * act_b);       // later: Xb rows 0..4095
    bf16_t* qb = (bf16_t*)(ws + 4 * act_b);       // later: Hb rows 0..4095
    bf16_t* kb = (bf16_t*)(ws + 5 * act_b);       // later: Hb rows 4096..8191
    bf16_t* Vt = (bf16_t*)(ws + 6 * act_b);
    bf16_t* vb = (bf16_t*)(ws + 7 * act_b);
    bf16_t* Wt[7];
    for (int i = 0; i < 7; ++i) Wt[i] = (bf16_t*)(ws + 8 * act_b + (size_t)i * wt_b);
    float* dPos = (float*)(ws + 8 * act_b + 7 * wt_b);
    float* dNeg = dPos + 512;
    bf16_t* Vpb = Qb;
    bf16_t* Vnb = Kb;
    bf16_t* Xb = Vb;  // spans 2*act_b (rows 0..8191)
    bf16_t* Hb = qb;  // spans qb+kb (contiguous 2*act_b)

    // 1. prep: convert Q,K,V + transpose weights + extract diags (one dispatch)
    PrepPtrs pp;
    pp.csrc[0] = Q; pp.csrc[1] = K; pp.csrc[2] = V;
    pp.cdst[0] = Qb; pp.cdst[1] = Kb; pp.cdst[2] = Vb;
    pp.wsrc[0] = W_q; pp.wsrc[1] = W_k; pp.wsrc[2] = W_v;
    pp.wsrc[3] = W_o; pp.wsrc[4] = W_o2; pp.wsrc[5] = w1; pp.wsrc[6] = w2;
    for (int i = 0; i < 7; ++i) pp.wdst[i] = Wt[i];
    pp.dsrc[0] = Wpos; pp.dsrc[1] = Wneg;
    pp.ddst[0] = dPos; pp.ddst[1] = dNeg;
    prep_kernel<<<8642, 256, 0, stream>>>(pp);

    // 2. q/k/v projections (batched z=3), bf16 out, all coalesced row-major
    {
        GemmB g = {};
        g.A[0] = Qb; g.A[1] = Kb; g.A[2] = Vb;
        g.Bt[0] = Wt[0]; g.Bt[1] = Wt[1]; g.Bt[2] = Wt[2];
        g.Cb[0] = qb; g.Cb[1] = kb; g.Cb[2] = vb;
        gemm2<false, false, 0, 1><<<dim3(8, 32, 3), 256, 0, stream>>>(g, 4096, 768, 768);
    }

    // 3. V transpose for PV (coalesced LDS-bounce, ~4 us)
    transpose_v_kernel<<<dim3(16, 2, 96), dim3(32, 8), 0, stream>>>(vb, Vt);

    // 4. attention v6 (64 q-rows/block; 768 blocks = exactly 3/CU, one pass)
    attn_kernel<<<dim3(96, 8), 256, 0, stream>>>(qb, kb, Vt, dPos, dNeg, Vpb, Vnb);

    // 5. out projections + residual Q -> Xb (bf16), batched z=2
    {
        GemmB g = {};
        g.A[0] = Vpb; g.A[1] = Vnb;
        g.Bt[0] = Wt[3]; g.Bt[1] = Wt[4];
        g.Res[0] = Q; g.Res[1] = Q;
        g.Cb[0] = Xb; g.Cb[1] = Xb + (size_t)4096 * 768;
        gemm2<false, false, 1, 1><<<dim3(8, 32, 2), 256, 0, stream>>>(g, 4096, 768, 768);
    }

    // 6. FFN1: relu(X @ w1 + b1), M=8192, bf16 out
    {
        GemmB g = {};
        g.A[0] = Xb;
        g.Bt[0] = Wt[5];
        g.bias = b1;
        g.Cb[0] = Hb;
        gemm2<true, true, 0, 1><<<dim3(8, 64, 1), 256, 0, stream>>>(g, 8192, 768, 768);
    }

    // 7. FFN2: H @ w2 + b2 + X(bf16) -> out (f32), M=8192, writes d_out
    {
        GemmB g = {};
        g.A[0] = Hb;
        g.Bt[0] = Wt[6];
        g.bias = b2;
        g.ResB[0] = Xb;
        g.Cf[0] = out;
        gemm2<true, false, 2, 0><<<dim3(8, 64, 1), 256, 0, stream>>>(g, 8192, 768, 768);
    }
}

// Round 11
// 116.401 us; speedup vs baseline: 1.0483x; 1.0483x over previous
//
#include <hip/hip_runtime.h>
#include <hip/hip_bf16.h>
#include <math.h>

typedef __bf16 bf16_t;
typedef __bf16 bf16x4 __attribute__((ext_vector_type(4)));
typedef __bf16 bf16x8 __attribute__((ext_vector_type(8)));
typedef float f32x4 __attribute__((ext_vector_type(4)));

#define MFMA16(a, b, c) __builtin_amdgcn_mfma_f32_16x16x32_bf16((a), (b), (c), 0, 0, 0)
#define EXP2F(x) __builtin_amdgcn_exp2f(x)

__device__ __forceinline__ void gll16(const void* g, void* lds) {
    __builtin_amdgcn_global_load_lds((const __attribute__((address_space(1))) void*)g,
                                     (__attribute__((address_space(3))) void*)lds, 16, 0, 0);
}

// ---------------------------------------------------------------------------
// Prep kernel: blocks [0,4032): transpose+convert 7 weights (576 blocks each);
// blocks 4032/4033: extract diag(W_pos)*SC / -diag(W_neg)*SC as f32 arrays.
// (QKV f32 is consumed directly by the qkv GEMM via f32 gll16 staging.)
// ---------------------------------------------------------------------------
struct PrepPtrs {
    const float* wsrc[7];
    bf16_t* wdst[7];
    const float* dsrc[2];
    float* ddst[2];
};

__global__ __launch_bounds__(256) void prep_kernel(PrepPtrs p) {
    const int bx = blockIdx.x, tid = threadIdx.x;
    if (bx < 4032) {
        __shared__ float t[32][33];
        const int wz = bx / 576, rem = bx - wz * 576;
        const int bxx = rem % 24, byy = rem / 24;
        const float* src = p.wsrc[wz];
        bf16_t* dst = p.wdst[wz];
        const int tx = tid & 31, ty = tid >> 5;
        const int x = bxx * 32 + tx;
        const int y0 = byy * 32;
#pragma unroll
        for (int j = 0; j < 4; ++j)
            t[ty + j * 8][tx] = src[(size_t)(y0 + ty + j * 8) * 768 + x];
        __syncthreads();
        const int ox = byy * 32 + tx;
        const int oy0 = bxx * 32;
#pragma unroll
        for (int j = 0; j < 4; ++j)
            dst[(size_t)(oy0 + ty + j * 8) * 768 + ox] = (bf16_t)t[tx][ty + j * 8];
    } else {
        const int s = bx - 4032;
        const float SC = 1.4426950408889634f / (8.0f + 1e-6f);
        const float sc = s ? -SC : SC;
        const float* src = p.dsrc[s];
        float* dst = p.ddst[s];
        for (int i = tid; i < 512; i += 256) dst[i] = src[(size_t)i * 513] * sc;
    }
}

// ---------------------------------------------------------------------------
// GEMM: C[M,N] = A[M,K] @ Bt[N,K]^T, BM=128 x BN=96 x BK=64, 4 waves
// (2x2, wave sub-tile 64x48, acc[4][3]). N=768 = 8 col-tiles -> grids are
// exact multiples of 256 blocks = zero tail at 2-3 blocks/CU.
// ALL staging via global_load_lds (fire-and-forget; reg-staging regressed r9).
// AF32: A staged as f32 (32 KB LDS tile), converted bf16 at fragment read
// (2x ds_read_b128 + cvt_pk; broadcast across 16-lane groups, XOR involution
// keeps it conflict-free). Non-AF32: bf16 A tile (16 KB).
// XCD-bijective block swizzle keeps A-row-panels + weight in one XCD's L2.
// RESMODE: 0 none, 1 f32 residual, 2 bf16 residual. OUTMODE: 0 f32, 1 bf16.
// VTZ: z==2 writes Vt[bh][d][l] directly (r8 vs r10 A/B: scatter-epilogue is
// ~2us cheaper than coalesced store + separate transpose kernel).
// ---------------------------------------------------------------------------
struct GemmB {
    const void* A[3];
    const bf16_t* Bt[3];
    const float* bias;
    const float* Res[3];
    const bf16_t* ResB[3];
    float* Cf[3];
    bf16_t* Cb[3];
    bf16_t* VtOut;
};

template <bool AF32, bool HAS_BIAS, bool RELU, int RESMODE, int OUTMODE, bool VTZ = false>
__global__ __launch_bounds__(256, 3) void gemm2(GemmB p, int M, int K, int N) {
    constexpr int NA = AF32 ? 8 : 4;  // gll16 segments per thread for A
    __shared__ __align__(16) char AsRaw[AF32 ? 128 * 64 * 4 : 128 * 64 * 2];
    __shared__ __align__(16) bf16_t Bs[96 * 64];  // 12 KB, rows of 128 B
    const int z = blockIdx.z;
    const bf16_t* __restrict__ Bt = p.Bt[z];
    const int tid = threadIdx.x, w = tid >> 6, l = tid & 63, l16 = l & 15, lk = l >> 4;
    const int wr = w >> 1, wc = w & 1;

    // XCD-bijective swizzle (nwg % 8 == 0 in all launches here)
    const int gx = gridDim.x, nwg = gx * gridDim.y;
    int flat = blockIdx.x + gx * blockIdx.y;
    flat = (flat & 7) * (nwg >> 3) + (flat >> 3);
    const int row0 = (flat / gx) * 128, col0 = (flat % gx) * 96;
    f32x4 acc[4][3] = {};

    const int lofs = l * 16;  // byte offset within a 1KB segment
    size_t aEl[NA];
    size_t bEl[3];
    if constexpr (AF32) {
#pragma unroll
        for (int i = 0; i < 8; ++i) {
            const int off = (w * 8 + i) * 1024 + lofs;
            const int row = off >> 8;                 // 256 B rows (64 f32)
            const int slot = (off >> 4) & 15;
            aEl[i] = (size_t)(row0 + row) * K + (size_t)((slot ^ (row & 15)) * 4);
        }
    } else {
#pragma unroll
        for (int i = 0; i < 4; ++i) {
            const int off = (w * 4 + i) * 1024 + lofs;
            const int row = off >> 7;                 // 128 B rows (64 bf16)
            const int ch = ((off >> 4) & 7) ^ (row & 7);
            aEl[i] = (size_t)(row0 + row) * K + ch * 8;
        }
    }
#pragma unroll
    for (int i = 0; i < 3; ++i) {
        const int off = (w * 3 + i) * 1024 + lofs;
        const int row = off >> 7;
        const int ch = ((off >> 4) & 7) ^ (row & 7);
        bEl[i] = (size_t)(col0 + row) * K + ch * 8;
    }

    for (int k0 = 0; k0 < K; k0 += 64) {
        __syncthreads();
        if constexpr (AF32) {
            const float* __restrict__ Af = (const float*)p.A[z];
#pragma unroll
            for (int i = 0; i < 8; ++i)
                gll16(Af + aEl[i] + k0, AsRaw + (w * 8 + i) * 1024);
        } else {
            const bf16_t* __restrict__ A = (const bf16_t*)p.A[z];
#pragma unroll
            for (int i = 0; i < 4; ++i)
                gll16(A + aEl[i] + k0, AsRaw + (w * 4 + i) * 1024);
        }
#pragma unroll
        for (int i = 0; i < 3; ++i)
            gll16(Bt + bEl[i] + k0, (char*)Bs + (w * 3 + i) * 1024);
        __syncthreads();

#pragma unroll
        for (int kk = 0; kk < 2; ++kk) {
            bf16x8 af[4], bfr[3];
#pragma unroll
            for (int mt = 0; mt < 4; ++mt) {
                const int ar = wr * 64 + mt * 16 + l16;
                if constexpr (AF32) {
                    const int s0 = kk * 8 + lk * 2;
                    const f32x4 u =
                        *(const f32x4*)(AsRaw + ar * 256 + ((s0 ^ (ar & 15)) << 4));
                    const f32x4 v =
                        *(const f32x4*)(AsRaw + ar * 256 + (((s0 + 1) ^ (ar & 15)) << 4));
                    bf16x8 o;
                    o[0] = (bf16_t)u[0]; o[1] = (bf16_t)u[1];
                    o[2] = (bf16_t)u[2]; o[3] = (bf16_t)u[3];
                    o[4] = (bf16_t)v[0]; o[5] = (bf16_t)v[1];
                    o[6] = (bf16_t)v[2]; o[7] = (bf16_t)v[3];
                    af[mt] = o;
                } else {
                    af[mt] = *(const bf16x8*)(AsRaw + ar * 128 +
                                              (((kk * 4 + lk) ^ (ar & 7)) << 4));
                }
            }
#pragma unroll
            for (int nt = 0; nt < 3; ++nt) {
                const int br = wc * 48 + nt * 16 + l16;
                bfr[nt] = *(const bf16x8*)((const char*)Bs + br * 128 +
                                           (((kk * 4 + lk) ^ (br & 7)) << 4));
            }
#pragma unroll
            for (int mt = 0; mt < 4; ++mt)
#pragma unroll
                for (int nt = 0; nt < 3; ++nt)
                    acc[mt][nt] = MFMA16(af[mt], bfr[nt], acc[mt][nt]);
        }
    }

    if constexpr (VTZ) {
        if (z == 2) {
            // write v in Vt[bh][d][l] layout: row = b*512 + l, col = h*64 + d
            const int b = row0 >> 9;
            const int lb0 = (row0 & 511) + wr * 64;
#pragma unroll
            for (int mt = 0; mt < 4; ++mt)
#pragma unroll
                for (int nt = 0; nt < 3; ++nt) {
                    const int col = col0 + wc * 48 + nt * 16 + l16;
                    const int hh = col >> 6, dd = col & 63;
                    bf16x4 v;
#pragma unroll
                    for (int i = 0; i < 4; ++i) v[i] = (bf16_t)acc[mt][nt][i];
                    const size_t o =
                        (((size_t)(b * 12 + hh) * 64 + dd) << 9) + lb0 + mt * 16 + lk * 4;
                    *(bf16x4*)(p.VtOut + o) = v;
                }
            return;
        }
    }

#pragma unroll
    for (int mt = 0; mt < 4; ++mt)
#pragma unroll
        for (int nt = 0; nt < 3; ++nt)
#pragma unroll
            for (int i = 0; i < 4; ++i) {
                const int row = row0 + wr * 64 + mt * 16 + lk * 4 + i;
                const int col = col0 + wc * 48 + nt * 16 + l16;
                float val = acc[mt][nt][i];
                if constexpr (HAS_BIAS) val += p.bias[col];
                if constexpr (RELU) val = fmaxf(val, 0.0f);
                const size_t o = (size_t)row * N + col;
                if constexpr (RESMODE == 1) val += p.Res[z][o];
                if constexpr (RESMODE == 2) val += (float)p.ResB[z][o];
                if constexpr (OUTMODE == 0) p.Cf[z][o] = val;
                else p.Cb[z][o] = (bf16_t)val;
            }
}

// ---------------------------------------------------------------------------
// Fused dual-softmax attention v6. Block = (bh, 64 q-rows), 4 waves:
// wave = (row-half, sign); each wave owns 32 q-rows x all keys x one sign.
// 8 chunks of 64 keys; K/Vt double-buffered in LDS (gll16 + XOR involution);
// stage(c+1) issued before compute(c). 32 MFMA per barrier; K/V ds_reads
// shared across the wave's two 16-row groups. Grid (96,8) = 768 blocks =
// exactly 3/CU, single pass. diag scales pre-packed as f32 (coalesced).
// No max pass (logits bounded, validated r2-r10).
// ---------------------------------------------------------------------------
__global__ __launch_bounds__(256, 3) void attn_kernel(const bf16_t* __restrict__ qb,
                                                      const bf16_t* __restrict__ kb,
                                                      const bf16_t* __restrict__ Vt,
                                                      const float* __restrict__ dPos,
                                                      const float* __restrict__ dNeg,
                                                      bf16_t* __restrict__ Vpb,
                                                      bf16_t* __restrict__ Vnb) {
    __shared__ __align__(16) bf16_t Ks[2][64 * 64];  // 2 x 8 KB (64 key-rows x 128 B)
    __shared__ __align__(16) bf16_t Vs[2][64 * 64];  // 2 x 8 KB (64 d-rows x 128 B)
    __shared__ __align__(16) bf16_t Ps[4][32][72];   // 18 KB wave-private P
    const int tid = threadIdx.x, w = tid >> 6, l = tid & 63, l16 = l & 15, lk = l >> 4;
    const int rh = w >> 1, sgn = w & 1;
    const int bh = blockIdx.x, qt = blockIdx.y, b = bh / 12, h = bh % 12;
    const int q0 = qt * 64 + rh * 32;
    const float* __restrict__ Wd = sgn ? dNeg : dPos;

    // Q fragments for this wave's 32 rows (2 row-groups), loaded once
    const size_t qbase = ((size_t)(b * 512 + q0)) * 768 + h * 64;
    bf16x8 qf[2][2];
#pragma unroll
    for (int rt = 0; rt < 2; ++rt)
#pragma unroll
        for (int ks = 0; ks < 2; ++ks)
            qf[rt][ks] =
                *(const bf16x8*)(qb + qbase + (size_t)(rt * 16 + l16) * 768 + ks * 32 + lk * 8);

    // staging source offsets (pre-swizzled); wave stages segs {2w, 2w+1}
    const size_t kbase0 = ((size_t)b * 512) * 768 + h * 64;
    const size_t vtb = (size_t)bh * 64 * 512;
    size_t kEl[2], vEl[2];
    int seg[2];
#pragma unroll
    for (int i = 0; i < 2; ++i) {
        seg[i] = w * 2 + i;
        const int off = seg[i] * 1024 + l * 16;
        const int row = off >> 7, slot = (off >> 4) & 7;
        kEl[i] = (size_t)row * 768 + (size_t)((slot ^ (row & 7)) * 8);
        vEl[i] = (size_t)row * 512 + (size_t)((slot ^ (row & 7)) * 8);
    }

    auto stage = [&](int c, int buf) {
#pragma unroll
        for (int i = 0; i < 2; ++i) {
            gll16(kb + kbase0 + (size_t)c * 64 * 768 + kEl[i], (char*)&Ks[buf][0] + seg[i] * 1024);
            gll16(Vt + vtb + (size_t)c * 64 + vEl[i], (char*)&Vs[buf][0] + seg[i] * 1024);
        }
    };

    f32x4 pacc[2][4] = {};
    float sm[2][4] = {};

    stage(0, 0);
    __syncthreads();

    for (int c = 0; c < 8; ++c) {
        const int buf = c & 1;
        if (c < 7) stage(c + 1, buf ^ 1);

        float dv[4];
#pragma unroll
        for (int nt = 0; nt < 4; ++nt) dv[nt] = Wd[c * 64 + nt * 16 + l16];

        // --- QK^T on staged K: 8 ds_reads feed 16 MFMA (shared across rt) ---
        f32x4 sacc[2][4] = {};
        __builtin_amdgcn_s_setprio(1);
#pragma unroll
        for (int nt = 0; nt < 4; ++nt) {
            const int kr = nt * 16 + l16;
            const bf16x8 kv0 =
                *(const bf16x8*)((const char*)&Ks[buf][0] + kr * 128 + ((lk ^ (kr & 7)) << 4));
            const bf16x8 kv1 =
                *(const bf16x8*)((const char*)&Ks[buf][0] + kr * 128 + (((4 + lk) ^ (kr & 7)) << 4));
            sacc[0][nt] = MFMA16(qf[0][0], kv0, sacc[0][nt]);
            sacc[0][nt] = MFMA16(qf[0][1], kv1, sacc[0][nt]);
            sacc[1][nt] = MFMA16(qf[1][0], kv0, sacc[1][nt]);
            sacc[1][nt] = MFMA16(qf[1][1], kv1, sacc[1][nt]);
        }
        __builtin_amdgcn_s_setprio(0);

        // --- exp2 (no max; logits bounded), store P, accumulate sums ---
#pragma unroll
        for (int rt = 0; rt < 2; ++rt)
#pragma unroll
            for (int nt = 0; nt < 4; ++nt)
#pragma unroll
                for (int i = 0; i < 4; ++i) {
                    const float e = EXP2F(sacc[rt][nt][i] * dv[nt]);
                    Ps[w][rt * 16 + lk * 4 + i][nt * 16 + l16] = (bf16_t)e;
                    sm[rt][i] += e;
                }

        // --- PV on staged V: 8 V ds_reads feed 16 MFMA (shared across rt) ---
        __builtin_amdgcn_s_setprio(1);
#pragma unroll
        for (int kt = 0; kt < 2; ++kt) {
            const bf16x8 pa0 = *(const bf16x8*)&Ps[w][l16][kt * 32 + lk * 8];
            const bf16x8 pa1 = *(const bf16x8*)&Ps[w][16 + l16][kt * 32 + lk * 8];
#pragma unroll
            for (int nd = 0; nd < 4; ++nd) {
                const int dr = nd * 16 + l16;
                const bf16x8 vv = *(const bf16x8*)((const char*)&Vs[buf][0] + dr * 128 +
                                                   (((kt * 4 + lk) ^ (dr & 7)) << 4));
                pacc[0][nd] = MFMA16(pa0, vv, pacc[0][nd]);
                pacc[1][nd] = MFMA16(pa1, vv, pacc[1][nd]);
            }
        }
        __builtin_amdgcn_s_setprio(0);

        if (c < 7) __syncthreads();  // drains vmcnt (stage c+1) + guards buf reuse
    }

    // --- finish row sums (keys spread across l16 lanes only) ---
#pragma unroll
    for (int off = 1; off < 16; off <<= 1)
#pragma unroll
        for (int rt = 0; rt < 2; ++rt)
#pragma unroll
            for (int i = 0; i < 4; ++i) sm[rt][i] += __shfl_xor(sm[rt][i], off, 64);

    // --- normalize + store this wave's complete 32x64 output ---
    bf16_t* __restrict__ Out = sgn ? Vnb : Vpb;
#pragma unroll
    for (int rt = 0; rt < 2; ++rt)
#pragma unroll
        for (int i = 0; i < 4; ++i) {
            const float r = (sgn ? -1.0f : 1.0f) / sm[rt][i];
            const size_t o = ((size_t)(b * 512 + q0 + rt * 16 + lk * 4 + i)) * 768 + h * 64;
#pragma unroll
            for (int nd = 0; nd < 4; ++nd) Out[o + nd * 16 + l16] = (bf16_t)(pacc[rt][nd][i] * r);
        }
}

// ---------------------------------------------------------------------------
extern "C" void kernel_launch(void* const* d_in, const int* in_sizes, int n_in,
                              void* d_out, int out_size, void* d_ws, size_t ws_size,
                              hipStream_t stream) {
    const float* Q = (const float*)d_in[0];
    const float* K = (const float*)d_in[1];
    const float* V = (const float*)d_in[2];
    const float* W_q = (const float*)d_in[3];
    const float* W_k = (const float*)d_in[4];
    const float* W_v = (const float*)d_in[5];
    const float* Wpos = (const float*)d_in[6];
    const float* Wneg = (const float*)d_in[7];
    const float* W_o = (const float*)d_in[8];
    const float* W_o2 = (const float*)d_in[9];
    const float* w1 = (const float*)d_in[10];
    const float* b1 = (const float*)d_in[11];
    const float* w2 = (const float*)d_in[12];
    const float* b2 = (const float*)d_in[13];
    float* out = (float*)d_out;

    char* ws = (char*)d_ws;
    const size_t act_b = (size_t)4096 * 768 * 2;  // 6.29 MB
    const size_t wt_b = (size_t)768 * 768 * 2;
    bf16_t* Vpb = (bf16_t*)(ws + 0 * act_b);
    bf16_t* Vnb = (bf16_t*)(ws + 1 * act_b);
    bf16_t* Xb = (bf16_t*)(ws + 2 * act_b);   // rows 0..8191 (2 act_b)
    bf16_t* qb = (bf16_t*)(ws + 4 * act_b);   // later: Hb rows 0..4095
    bf16_t* kb = (bf16_t*)(ws + 5 * act_b);   // later: Hb rows 4096..8191
    bf16_t* Vt = (bf16_t*)(ws + 6 * act_b);
    bf16_t* Wt[7];
    for (int i = 0; i < 7; ++i) Wt[i] = (bf16_t*)(ws + 7 * act_b + (size_t)i * wt_b);
    float* dPos = (float*)(ws + 7 * act_b + 7 * wt_b);
    float* dNeg = dPos + 512;
    bf16_t* Hb = qb;  // spans qb+kb (contiguous 2*act_b)

    // 1. prep: transpose weights + extract diags (no QKV convert pass)
    PrepPtrs pp;
    pp.wsrc[0] = W_q; pp.wsrc[1] = W_k; pp.wsrc[2] = W_v;
    pp.wsrc[3] = W_o; pp.wsrc[4] = W_o2; pp.wsrc[5] = w1; pp.wsrc[6] = w2;
    for (int i = 0; i < 7; ++i) pp.wdst[i] = Wt[i];
    pp.dsrc[0] = Wpos; pp.dsrc[1] = Wneg;
    pp.ddst[0] = dPos; pp.ddst[1] = dNeg;
    prep_kernel<<<4034, 256, 0, stream>>>(pp);

    // 2. q/k/v projections from f32 inputs (f32 gll16 A-staging, cvt at
    //    fragment read), batched z=3, bf16 out; z==2 writes Vt directly
    {
        GemmB g = {};
        g.A[0] = Q; g.A[1] = K; g.A[2] = V;
        g.Bt[0] = Wt[0]; g.Bt[1] = Wt[1]; g.Bt[2] = Wt[2];
        g.Cb[0] = qb; g.Cb[1] = kb;
        g.VtOut = Vt;
        gemm2<true, false, false, 0, 1, true><<<dim3(8, 32, 3), 256, 0, stream>>>(g, 4096, 768, 768);
    }

    // 3. attention v6 (64 q-rows/block; 768 blocks = exactly 3/CU, one pass)
    attn_kernel<<<dim3(96, 8), 256, 0, stream>>>(qb, kb, Vt, dPos, dNeg, Vpb, Vnb);

    // 4. out projections + residual Q (f32) -> Xb (bf16), batched z=2
    {
        GemmB g = {};
        g.A[0] = Vpb; g.A[1] = Vnb;
        g.Bt[0] = Wt[3]; g.Bt[1] = Wt[4];
        g.Res[0] = Q; g.Res[1] = Q;
        g.Cb[0] = Xb; g.Cb[1] = Xb + (size_t)4096 * 768;
        gemm2<false, false, false, 1, 1><<<dim3(8, 32, 2), 256, 0, stream>>>(g, 4096, 768, 768);
    }

    // 5. FFN1: relu(X @ w1 + b1), M=8192, bf16 out
    {
        GemmB g = {};
        g.A[0] = Xb;
        g.Bt[0] = Wt[5];
        g.bias = b1;
        g.Cb[0] = Hb;
        gemm2<false, true, true, 0, 1><<<dim3(8, 64, 1), 256, 0, stream>>>(g, 8192, 768, 768);
    }

    // 6. FFN2: H @ w2 + b2 + X(bf16) -> out (f32), M=8192, writes d_out
    {
        GemmB g = {};
        g.A[0] = Hb;
        g.Bt[0] = Wt[6];
        g.bias = b2;
        g.ResB[0] = Xb;
        g.Cf[0] = out;
        gemm2<false, true, false, 2, 0><<<dim3(8, 64, 1), 256, 0, stream>>>(g, 8192, 768, 768);
    }
}